// Round 2
// baseline (308.449 us; speedup 1.0000x reference)
//
#include <hip/hip_runtime.h>

// Sinkhorn loss, single-pass moment formulation.
//
// Collapsed math (argsort = identity since cumsums are non-decreasing, and
// weights w=arange give identical mass breakpoints for x and y):
//   s_t = relu(v_t); X_t = cumsum(s); Sx = sum_t X_t
//   loss_p = sum_t t * (X_t/Sx - Y_t/Sy)^2 ;  out = sum_p loss_p
//
// Chunked expansion (chunk j, local cumsums L,M; offsets O_j,P_j):
//   X_t = O_j + L_i,  g = isx*O - isy*P
//   sum_{t in j} t*(isx*X - isy*Y)^2
//     = g^2*T_j + 2g*(isx*pL - isy*pM) + isx^2*pLL - 2*isx*isy*pLM + isy^2*pMM
// with chunk-local moments pL=sum t*L, pLL=sum t*L^2, pLM=sum t*L*M,
// uL=sum L (Sx = sum_j 64*O_j + uL_j), T_j = 4096*j + 2016.
// => pass 1 never needs Sx/Sy: single read of the 128 MiB inputs.

#define NT   4096
#define NP   4096
#define CH   64     // number of t-chunks
#define LCH  64     // chunk length; CH*LCH == NT
#define BLK  256
#define BLK2 64

__global__ __launch_bounds__(BLK) void p1_moments(
    const float* __restrict__ x, const float* __restrict__ y,
    float* __restrict__ aX, float* __restrict__ aY,
    float* __restrict__ uL, float* __restrict__ uM,
    float* __restrict__ pL, float* __restrict__ pM,
    float* __restrict__ pLL, float* __restrict__ pMM,
    float* __restrict__ pLM)
{
  const int pv = blockIdx.x * BLK + threadIdx.x;  // 0 .. NP/2-1
  const int p0 = pv * 2;
  const int j  = blockIdx.y;
  const int t0 = j * LCH;
  const float* xb = x + (size_t)t0 * NP + p0;
  const float* yb = y + (size_t)t0 * NP + p0;

  double cx0 = 0, cx1 = 0, cy0 = 0, cy1 = 0;
  double uL0 = 0, uL1 = 0, uM0 = 0, uM1 = 0;
  double pL0 = 0, pL1 = 0, pM0 = 0, pM1 = 0;
  double pLL0 = 0, pLL1 = 0, pMM0 = 0, pMM1 = 0, pLM0 = 0, pLM1 = 0;

#pragma unroll 8
  for (int i = 0; i < LCH; ++i) {
    const float2 xv = *(const float2*)(xb + (size_t)i * NP);
    const float2 yv = *(const float2*)(yb + (size_t)i * NP);
    const double td = (double)(t0 + i);

    const double lx0 = (double)fmaxf(xv.x, 0.f);
    const double lx1 = (double)fmaxf(xv.y, 0.f);
    const double ly0 = (double)fmaxf(yv.x, 0.f);
    const double ly1 = (double)fmaxf(yv.y, 0.f);

    cx0 += lx0; cy0 += ly0;
    const double tl0 = td * cx0;
    const double tm0 = td * cy0;
    pL0  += tl0;        pM0  += tm0;
    pLL0 += tl0 * cx0;  pMM0 += tm0 * cy0;
    pLM0 += tl0 * cy0;
    uL0  += cx0;        uM0  += cy0;

    cx1 += lx1; cy1 += ly1;
    const double tl1 = td * cx1;
    const double tm1 = td * cy1;
    pL1  += tl1;        pM1  += tm1;
    pLL1 += tl1 * cx1;  pMM1 += tm1 * cy1;
    pLM1 += tl1 * cy1;
    uL1  += cx1;        uM1  += cy1;
  }

  const size_t o = (size_t)j * NP + p0;
  aX[o]  = (float)cx0;  aX[o+1]  = (float)cx1;
  aY[o]  = (float)cy0;  aY[o+1]  = (float)cy1;
  uL[o]  = (float)uL0;  uL[o+1]  = (float)uL1;
  uM[o]  = (float)uM0;  uM[o+1]  = (float)uM1;
  pL[o]  = (float)pL0;  pL[o+1]  = (float)pL1;
  pM[o]  = (float)pM0;  pM[o+1]  = (float)pM1;
  pLL[o] = (float)pLL0; pLL[o+1] = (float)pLL1;
  pMM[o] = (float)pMM0; pMM[o+1] = (float)pMM1;
  pLM[o] = (float)pLM0; pLM[o+1] = (float)pLM1;
}

__global__ __launch_bounds__(BLK2) void p2_loss(
    const float* __restrict__ aX, const float* __restrict__ aY,
    const float* __restrict__ uL, const float* __restrict__ uM,
    const float* __restrict__ pL, const float* __restrict__ pM,
    const float* __restrict__ pLL, const float* __restrict__ pMM,
    const float* __restrict__ pLM,
    double* __restrict__ part)
{
  const int p = blockIdx.x * BLK2 + threadIdx.x;

  double O = 0, P = 0, Sx = 0, Sy = 0;
#pragma unroll 8
  for (int j = 0; j < CH; ++j) {
    const size_t o = (size_t)j * NP + p;
    Sx += (double)LCH * O + (double)uL[o];
    Sy += (double)LCH * P + (double)uM[o];
    O  += (double)aX[o];
    P  += (double)aY[o];
  }
  const double isx = 1.0 / Sx;
  const double isy = 1.0 / Sy;

  O = 0; P = 0;
  double loss = 0;
#pragma unroll 4
  for (int j = 0; j < CH; ++j) {
    const size_t o = (size_t)j * NP + p;
    const double g  = isx * O - isy * P;
    const double Tj = 4096.0 * (double)j + 2016.0;
    const double sh  = isx * (double)pL[o] - isy * (double)pM[o];
    const double shh = isx * isx * (double)pLL[o]
                     - 2.0 * isx * isy * (double)pLM[o]
                     + isy * isy * (double)pMM[o];
    loss += g * g * Tj + 2.0 * g * sh + shh;
    O += (double)aX[o];
    P += (double)aY[o];
  }

  // wave-level reduce across the 64 lanes
  for (int s = 32; s > 0; s >>= 1)
    loss += __shfl_down(loss, s, 64);
  if (threadIdx.x == 0) part[blockIdx.x] = loss;
}

__global__ __launch_bounds__(BLK2) void p3_final(
    const double* __restrict__ part, float* __restrict__ out)
{
  double v = part[threadIdx.x];  // exactly 64 partials
  for (int s = 32; s > 0; s >>= 1)
    v += __shfl_down(v, s, 64);
  if (threadIdx.x == 0) out[0] = (float)v;
}

extern "C" void kernel_launch(void* const* d_in, const int* in_sizes, int n_in,
                              void* d_out, int out_size, void* d_ws, size_t ws_size,
                              hipStream_t stream) {
  const float* x = (const float*)d_in[0];
  const float* y = (const float*)d_in[1];
  float* out = (float*)d_out;

  const size_t CNP = (size_t)CH * NP;
  char* ws = (char*)d_ws;
  float* aX  = (float*)ws; ws += CNP * sizeof(float);
  float* aY  = (float*)ws; ws += CNP * sizeof(float);
  float* uL  = (float*)ws; ws += CNP * sizeof(float);
  float* uM  = (float*)ws; ws += CNP * sizeof(float);
  float* pL  = (float*)ws; ws += CNP * sizeof(float);
  float* pM  = (float*)ws; ws += CNP * sizeof(float);
  float* pLL = (float*)ws; ws += CNP * sizeof(float);
  float* pMM = (float*)ws; ws += CNP * sizeof(float);
  float* pLM = (float*)ws; ws += CNP * sizeof(float);
  double* part = (double*)ws; ws += (size_t)(NP / BLK2) * sizeof(double);

  dim3 g1((NP / 2) / BLK, CH);  // 8 x 64 = 512 blocks
  p1_moments<<<g1, BLK, 0, stream>>>(x, y, aX, aY, uL, uM, pL, pM, pLL, pMM, pLM);
  p2_loss<<<NP / BLK2, BLK2, 0, stream>>>(aX, aY, uL, uM, pL, pM, pLL, pMM, pLM, part);
  p3_final<<<1, BLK2, 0, stream>>>(part, out);
}

// Round 4
// 165.971 us; speedup vs baseline: 1.8585x; 1.8585x over previous
//
#include <hip/hip_runtime.h>

// Sinkhorn loss, single-pass moment formulation (see round-2 notes).
//   s_t = relu(v_t); X_t = cumsum(s); Sx = sum_t X_t
//   loss_p = sum_t t * (X_t/Sx - Y_t/Sy)^2 ;  out = sum_p loss_p
// Chunk j (local cumsums L,M; exclusive chunk offsets O,P; g = isx*O - isy*P):
//   sum_{t in j} t*(isx*X - isy*Y)^2
//     = g^2*T_j + 2g*(isx*pL - isy*pM) + isx^2*pLL - 2*isx*isy*pLM + isy^2*pMM
// Moments per (chunk, column) computed in ONE streaming read of x,y (f32
// accumulation: local cumsums <= 64 elements, error ~1e-5 abs on a 454 output).
// Combine kernel: one wave per column, lane = chunk, shuffle prefix-scan for
// O/P (round-2's serial-load combine was 1-outstanding-load latency-bound).

#define NT   4096
#define NP   4096
#define CH   64     // number of t-chunks == wave size
#define LCH  64     // chunk length; CH*LCH == NT
#define BLK  256

__global__ __launch_bounds__(BLK) void p1_moments(
    const float* __restrict__ x, const float* __restrict__ y,
    float* __restrict__ aX, float* __restrict__ aY,
    float* __restrict__ uL, float* __restrict__ uM,
    float* __restrict__ pL, float* __restrict__ pM,
    float* __restrict__ pLL, float* __restrict__ pMM,
    float* __restrict__ pLM)
{
  const int pv = blockIdx.x * BLK + threadIdx.x;  // 0 .. NP/2-1 (float2 col)
  const int j  = blockIdx.y;
  const int t0 = j * LCH;
  const float2* xb = (const float2*)x + (size_t)t0 * (NP / 2) + pv;
  const float2* yb = (const float2*)y + (size_t)t0 * (NP / 2) + pv;

  float cx0 = 0.f, cx1 = 0.f, cy0 = 0.f, cy1 = 0.f;
  float uL0 = 0.f, uL1 = 0.f, uM0 = 0.f, uM1 = 0.f;
  float pL0 = 0.f, pL1 = 0.f, pM0 = 0.f, pM1 = 0.f;
  float pLL0 = 0.f, pLL1 = 0.f, pMM0 = 0.f, pMM1 = 0.f;
  float pLM0 = 0.f, pLM1 = 0.f;

#pragma unroll 8
  for (int i = 0; i < LCH; ++i) {
    const float2 xv = xb[(size_t)i * (NP / 2)];
    const float2 yv = yb[(size_t)i * (NP / 2)];
    const float t = (float)(t0 + i);

    const float lx0 = fmaxf(xv.x, 0.f), lx1 = fmaxf(xv.y, 0.f);
    const float ly0 = fmaxf(yv.x, 0.f), ly1 = fmaxf(yv.y, 0.f);

    cx0 += lx0; cy0 += ly0;
    const float tl0 = t * cx0, tm0 = t * cy0;
    pL0  += tl0;                  pM0  += tm0;
    pLL0 = fmaf(tl0, cx0, pLL0);  pMM0 = fmaf(tm0, cy0, pMM0);
    pLM0 = fmaf(tl0, cy0, pLM0);
    uL0  += cx0;                  uM0  += cy0;

    cx1 += lx1; cy1 += ly1;
    const float tl1 = t * cx1, tm1 = t * cy1;
    pL1  += tl1;                  pM1  += tm1;
    pLL1 = fmaf(tl1, cx1, pLL1);  pMM1 = fmaf(tm1, cy1, pMM1);
    pLM1 = fmaf(tl1, cy1, pLM1);
    uL1  += cx1;                  uM1  += cy1;
  }

  const size_t o2 = (size_t)j * (NP / 2) + pv;
  ((float2*)aX)[o2]  = make_float2(cx0, cx1);
  ((float2*)aY)[o2]  = make_float2(cy0, cy1);
  ((float2*)uL)[o2]  = make_float2(uL0, uL1);
  ((float2*)uM)[o2]  = make_float2(uM0, uM1);
  ((float2*)pL)[o2]  = make_float2(pL0, pL1);
  ((float2*)pM)[o2]  = make_float2(pM0, pM1);
  ((float2*)pLL)[o2] = make_float2(pLL0, pLL1);
  ((float2*)pMM)[o2] = make_float2(pMM0, pMM1);
  ((float2*)pLM)[o2] = make_float2(pLM0, pLM1);
}

// One wave per column p; lane = chunk j. Shuffle prefix scan for O/P.
__global__ __launch_bounds__(BLK) void p2_loss(
    const float* __restrict__ aX, const float* __restrict__ aY,
    const float* __restrict__ uL, const float* __restrict__ uM,
    const float* __restrict__ pL, const float* __restrict__ pM,
    const float* __restrict__ pLL, const float* __restrict__ pMM,
    const float* __restrict__ pLM,
    double* __restrict__ part)
{
  const int wave = threadIdx.x >> 6;           // 4 waves per block
  const int lane = threadIdx.x & 63;           // = chunk j
  const int p    = blockIdx.x * 4 + wave;
  const size_t o = (size_t)lane * NP + p;

  const double a  = (double)aX[o];
  const double b  = (double)aY[o];
  const double ul = (double)uL[o];
  const double um = (double)uM[o];

  // inclusive scan -> exclusive offsets
  double sx = a, sy = b;
  for (int d = 1; d < 64; d <<= 1) {
    const double tx = __shfl_up(sx, d, 64);
    const double ty = __shfl_up(sy, d, 64);
    if (lane >= d) { sx += tx; sy += ty; }
  }
  const double O = sx - a;
  const double P = sy - b;

  // Sx = sum_j (LCH*O_j + uL_j), butterfly reduce (all lanes get total)
  double vx = (double)LCH * O + ul;
  double vy = (double)LCH * P + um;
  for (int m = 32; m; m >>= 1) {
    vx += __shfl_xor(vx, m, 64);
    vy += __shfl_xor(vy, m, 64);
  }
  const double isx = 1.0 / vx;
  const double isy = 1.0 / vy;

  const double g   = isx * O - isy * P;
  const double Tj  = 4096.0 * (double)lane + 2016.0;
  const double sh  = isx * (double)pL[o] - isy * (double)pM[o];
  const double shh = isx * isx * (double)pLL[o]
                   - 2.0 * isx * isy * (double)pLM[o]
                   + isy * isy * (double)pMM[o];
  double loss = g * g * Tj + 2.0 * g * sh + shh;

  for (int m = 32; m; m >>= 1) loss += __shfl_xor(loss, m, 64);
  if (lane == 0) part[p] = loss;
}

__global__ __launch_bounds__(1024) void p3_final(
    const double* __restrict__ part, float* __restrict__ out)
{
  __shared__ double red[1024];
  double v = 0.0;
  for (int i = threadIdx.x; i < NP; i += 1024) v += part[i];
  red[threadIdx.x] = v;
  __syncthreads();
  for (int s = 512; s > 0; s >>= 1) {
    if (threadIdx.x < s) red[threadIdx.x] += red[threadIdx.x + s];
    __syncthreads();
  }
  if (threadIdx.x == 0) out[0] = (float)red[0];
}

extern "C" void kernel_launch(void* const* d_in, const int* in_sizes, int n_in,
                              void* d_out, int out_size, void* d_ws, size_t ws_size,
                              hipStream_t stream) {
  const float* x = (const float*)d_in[0];
  const float* y = (const float*)d_in[1];
  float* out = (float*)d_out;

  const size_t CNP = (size_t)CH * NP;
  char* ws = (char*)d_ws;
  float* aX  = (float*)ws; ws += CNP * sizeof(float);
  float* aY  = (float*)ws; ws += CNP * sizeof(float);
  float* uL  = (float*)ws; ws += CNP * sizeof(float);
  float* uM  = (float*)ws; ws += CNP * sizeof(float);
  float* pL  = (float*)ws; ws += CNP * sizeof(float);
  float* pM  = (float*)ws; ws += CNP * sizeof(float);
  float* pLL = (float*)ws; ws += CNP * sizeof(float);
  float* pMM = (float*)ws; ws += CNP * sizeof(float);
  float* pLM = (float*)ws; ws += CNP * sizeof(float);
  double* part = (double*)ws; ws += (size_t)NP * sizeof(double);

  dim3 g1((NP / 2) / BLK, CH);  // 8 x 64 blocks, 2048 waves
  p1_moments<<<g1, BLK, 0, stream>>>(x, y, aX, aY, uL, uM, pL, pM, pLL, pMM, pLM);
  p2_loss<<<NP / 4, BLK, 0, stream>>>(aX, aY, uL, uM, pL, pM, pLL, pMM, pLM, part);
  p3_final<<<1, 1024, 0, stream>>>(part, out);
}